// Round 1
// baseline (145.073 us; speedup 1.0000x reference)
//
#include <hip/hip_runtime.h>
#include <hip/hip_bf16.h>

// ScaledDotProductAttention: B=2,H=16,D=64,N=2048, fp32 in/out.
// Layout per head: Q,K,V are D x N (N contiguous). scores = Q^T K / sqrt(N),
// P = softmax_k, out[q][v] = sum_k P[q][k] V[v][k], out is N x D.
// Max-free softmax (|scores| <~ 1.5, exp-safe).
// Round 4: 32x32x16 MFMA; P redistributed in-register via
// v_permlane32_swap_b32 (no LDS P staging; -18KB LDS, -12 LDS ops/iter,
// half the MFMA instruction count). Staging/double-buffer unchanged.

typedef __attribute__((ext_vector_type(8))) short short8;   // 8 bf16 (A/B frag)
typedef __attribute__((ext_vector_type(16))) float f32x16;  // 32x32 C/D frag

#define NN 2048
#define DD 64
#define ROWB 144   // LDS row: 64 bf16 (128 B) + 16 B pad; multiple of 16

#if __has_builtin(__builtin_amdgcn_exp2f)
#define EXP2(x) __builtin_amdgcn_exp2f(x)
#else
#define EXP2(x) __expf(0.69314718056f * (x))
#endif

__device__ __forceinline__ unsigned pk2(float a, float b) {
  __hip_bfloat162 hh = __float22bfloat162_rn(make_float2(a, b));  // a -> low short
  unsigned u; __builtin_memcpy(&u, &hh, 4); return u;
}
__device__ __forceinline__ short f2bf(float f) {
  union { float f; unsigned u; } x; x.f = f;
  unsigned r = (x.u + 0x7fffu + ((x.u >> 16) & 1u)) >> 16;  // RNE
  return (short)r;
}
// Swap high 32 lanes of x with low 32 lanes of y (gfx950).
__device__ __forceinline__ void pl32swap(unsigned &x, unsigned &y) {
  asm("v_permlane32_swap_b32 %0, %1" : "+v"(x), "+v"(y));
}

__global__ __launch_bounds__(256, 2) void attn_kernel(
    const float* __restrict__ Q, const float* __restrict__ K,
    const float* __restrict__ V, float* __restrict__ Out) {
  const int tid  = threadIdx.x;
  const int wave = tid >> 6, lane = tid & 63;
  const int m = lane & 31, h = lane >> 5;   // 32x32 frag coords

  const int bh   = blockIdx.x >> 4;   // 16 q-blocks per head (128 q rows each)
  const int qblk = blockIdx.x & 15;

  const float* Qh = Q + (size_t)bh * DD * NN;
  const float* Kh = K + (size_t)bh * DD * NN;
  const float* Vh = V + (size_t)bh * DD * NN;
  float*       Oh = Out + (size_t)bh * NN * DD;

  __shared__ __align__(16) char ldsK[2][64 * ROWB];   // KT: [key][d] bf16, xor-swizzled 16B groups
  __shared__ __align__(16) char ldsV[2][64 * ROWB];   // V:  [v][key] bf16, linear

  // ---- Q as B-fragments (32x32x16): B[k=h*8+j][n=m], k = d within 16-step ----
  const float qscale = 0.031881407f;  // log2(e)/sqrt(2048)
  const int qb = qblk * 128 + wave * 32;
  short8 bQ[4];
#pragma unroll
  for (int st = 0; st < 4; ++st)
#pragma unroll
    for (int j = 0; j < 8; ++j) {
      int d = st * 16 + h * 8 + j;
      bQ[st][j] = f2bf(Qh[(size_t)d * NN + qb + m] * qscale);
    }

  f32x16 accO[2];   // O[q][v]: col=v (m), row=q ((r&3)+8*(r>>2)+4*h)
#pragma unroll
  for (int vt = 0; vt < 2; ++vt)
#pragma unroll
    for (int i = 0; i < 16; ++i) accO[vt][i] = 0.f;
  float lp = 0.f;   // running sum of exp for q = qb + m (this lane's column)

  // staging assignments (unchanged from verified round 3)
  const int ka = tid & 31, kg = tid >> 5;        // K: d-pair (2*ka,2*ka+1), keys kg*8..+7
  const int vv = tid >> 2, vko = (tid & 3) * 16; // V: row v, 16 keys
  const float* kbase0 = Kh + (size_t)(2 * ka) * NN + kg * 8;
  const float* kbase1 = kbase0 + NN;
  const float* vbase  = Vh + (size_t)vv * NN + vko;

  float kA[8], kB[8], vA[16];
  auto load_kv = [&](int k0) {
    const float4* p0 = (const float4*)(kbase0 + k0);
    const float4* p1 = (const float4*)(kbase1 + k0);
    float4 a0 = p0[0], a1 = p0[1];
    float4 b0 = p1[0], b1 = p1[1];
    kA[0] = a0.x; kA[1] = a0.y; kA[2] = a0.z; kA[3] = a0.w;
    kA[4] = a1.x; kA[5] = a1.y; kA[6] = a1.z; kA[7] = a1.w;
    kB[0] = b0.x; kB[1] = b0.y; kB[2] = b0.z; kB[3] = b0.w;
    kB[4] = b1.x; kB[5] = b1.y; kB[6] = b1.z; kB[7] = b1.w;
    const float4* pv = (const float4*)(vbase + k0);
    float4 c0 = pv[0], c1 = pv[1], c2 = pv[2], c3 = pv[3];
    vA[0]  = c0.x; vA[1]  = c0.y; vA[2]  = c0.z; vA[3]  = c0.w;
    vA[4]  = c1.x; vA[5]  = c1.y; vA[6]  = c1.z; vA[7]  = c1.w;
    vA[8]  = c2.x; vA[9]  = c2.y; vA[10] = c2.z; vA[11] = c2.w;
    vA[12] = c3.x; vA[13] = c3.y; vA[14] = c3.z; vA[15] = c3.w;
  };
  auto store_kv = [&](char* bK, char* bV) {
#pragma unroll
    for (int j = 0; j < 8; ++j) {
      int k = kg * 8 + j;
      int grp = (ka >> 2) ^ ((k >> 1) & 7);
      *(unsigned*)&bK[k * ROWB + grp * 16 + (ka & 3) * 4] = pk2(kA[j], kB[j]);
    }
    uint4 w0 = make_uint4(pk2(vA[0], vA[1]),  pk2(vA[2], vA[3]),
                          pk2(vA[4], vA[5]),  pk2(vA[6], vA[7]));
    uint4 w1 = make_uint4(pk2(vA[8], vA[9]),  pk2(vA[10], vA[11]),
                          pk2(vA[12], vA[13]), pk2(vA[14], vA[15]));
    *(uint4*)&bV[vv * ROWB + vko * 2]      = w0;
    *(uint4*)&bV[vv * ROWB + vko * 2 + 16] = w1;
  };

  // ---- prologue: stage chunk 0 ----
  load_kv(0);
  store_kv(ldsK[0], ldsV[0]);
  __syncthreads();

  const int sw = (m >> 1) & 7;   // K read-side xor swizzle (same for rows m, 32+m)

  for (int it = 0; it < 32; ++it) {
    const int cur = it & 1;
    // prefetch next chunk into registers (wrapped on last iter; result unused)
    load_kv(((it + 1) & 31) * 64);

    const char* cK = ldsK[cur];
    const char* cV = ldsV[cur];

    // ---- S^T[key][q]: A = KT frag (key=row), B = Q regs; 2 key-tiles of 32 ----
    f32x16 sT0, sT1;
#pragma unroll
    for (int i = 0; i < 16; ++i) { sT0[i] = 0.f; sT1[i] = 0.f; }
#pragma unroll
    for (int st = 0; st < 4; ++st) {
      const int off = (((st * 2 + h) ^ sw) * 16);
      short8 aK0 = *(const short8*)&cK[m * ROWB + off];
      short8 aK1 = *(const short8*)&cK[(32 + m) * ROWB + off];
      sT0 = __builtin_amdgcn_mfma_f32_32x32x16_bf16(aK0, bQ[st], sT0, 0, 0, 0);
      sT1 = __builtin_amdgcn_mfma_f32_32x32x16_bf16(aK1, bQ[st], sT1, 0, 0, 0);
    }

    // ---- P = exp2(S'); keys for reg r: kt*32 + 8*(r>>2) + 4*h + (r&3) ----
    float p[2][16];
#pragma unroll
    for (int r = 0; r < 16; ++r) { p[0][r] = EXP2(sT0[r]); p[1][r] = EXP2(sT1[r]); }

    unsigned u[2][4][2];   // u[kt][g][c] = keys kt*32 + 8g + 4h + 2c + {0,1}
#pragma unroll
    for (int kt = 0; kt < 2; ++kt) {
#pragma unroll
      for (int g = 0; g < 4; ++g) {
        u[kt][g][0] = pk2(p[kt][4 * g + 0], p[kt][4 * g + 1]);
        u[kt][g][1] = pk2(p[kt][4 * g + 2], p[kt][4 * g + 3]);
      }
      float s0 = (p[kt][0]  + p[kt][1])  + (p[kt][2]  + p[kt][3]);
      float s1 = (p[kt][4]  + p[kt][5])  + (p[kt][6]  + p[kt][7]);
      float s2 = (p[kt][8]  + p[kt][9])  + (p[kt][10] + p[kt][11]);
      float s3 = (p[kt][12] + p[kt][13]) + (p[kt][14] + p[kt][15]);
      lp += (s0 + s1) + (s2 + s3);
    }

    // ---- A-frag assembly via permlane32_swap, then O += P V^T ----
    // PV A-frag (32x32x16): lane needs keys s*16 + 8h + j, j=0..7.
    // u32 c' of that frag: key bits -> g = 2*(s&1)+h_src... exchange with
    // lane+-32 supplies the h_src=1-h halves: (t[c], t[c+2]) = swap(u_ge[c], u_go[c]).
#pragma unroll
    for (int s = 0; s < 4; ++s) {
      const int kt = s >> 1, ge = 2 * (s & 1);
      unsigned t0 = u[kt][ge][0], t1 = u[kt][ge][1];
      unsigned t2 = u[kt][ge + 1][0], t3 = u[kt][ge + 1][1];
      pl32swap(t0, t2);
      pl32swap(t1, t3);
      short8 aP;
      { unsigned w[4] = {t0, t1, t2, t3}; __builtin_memcpy(&aP, w, 16); }
#pragma unroll
      for (int vt = 0; vt < 2; ++vt) {
        short8 bV = *(const short8*)&cV[(vt * 32 + m) * ROWB + s * 32 + h * 16];
        accO[vt] = __builtin_amdgcn_mfma_f32_32x32x16_bf16(aP, bV, accO[vt], 0, 0, 0);
      }
    }

    // ---- write prefetched chunk into the other buffer, single barrier ----
    store_kv(ldsK[cur ^ 1], ldsV[cur ^ 1]);
    __syncthreads();
  }

  // ---- epilogue: lane m and m+32 hold the same q; combine, normalize, store ----
  float lv = lp + __shfl_xor(lp, 32, 64);   // full l for q = qb + m, all lanes
#pragma unroll
  for (int r = 0; r < 16; ++r) {
    const int qrow = (r & 3) + 8 * (r >> 2) + 4 * h;
    const float linv = 1.0f / __shfl(lv, qrow, 64);
    float* op = Oh + (size_t)(qb + qrow) * DD + m;
    op[0]  = accO[0][r] * linv;
    op[32] = accO[1][r] * linv;
  }
}

extern "C" void kernel_launch(void* const* d_in, const int* in_sizes, int n_in,
                              void* d_out, int out_size, void* d_ws, size_t ws_size,
                              hipStream_t stream) {
  const float* Q = (const float*)d_in[0];
  const float* K = (const float*)d_in[1];
  const float* V = (const float*)d_in[2];
  float* O = (float*)d_out;
  dim3 grid(2 * 16 * (NN / 128));  // 512 blocks, 4 waves, 128 q-rows each
  attn_kernel<<<grid, dim3(256), 0, stream>>>(Q, K, V, O);
}

// Round 2
// 142.579 us; speedup vs baseline: 1.0175x; 1.0175x over previous
//
#include <hip/hip_runtime.h>
#include <hip/hip_bf16.h>

// ScaledDotProductAttention: B=2,H=16,D=64,N=2048, fp32 in/out.
// Layout per head: Q,K,V are D x N (N contiguous). scores = Q^T K / sqrt(N),
// P = softmax_k, out[q][v] = sum_k P[q][k] V[v][k], out is N x D.
// Max-free softmax (|scores| <~ 1.5, exp-safe).
// Round 5: occupancy fix. 16 q per wave -> 4096 waves = 16 waves/CU (was 8).
// 512-thread blocks (8 waves), grid stays 512 (FETCH unchanged). 16x16x32
// MFMA (short dep chains, R3 dataflow) + in-register P via
// permlane32_swap + permlane16_swap (no LDS P, no P round-trip).

typedef __attribute__((ext_vector_type(8))) short short8;   // 8 bf16 (A/B frag)
typedef __attribute__((ext_vector_type(4))) float f32x4;    // 16x16 C/D frag

#define NN 2048
#define DD 64
#define ROWB 144   // LDS row: 64 bf16 (128 B) + 16 B pad; multiple of 16

#if __has_builtin(__builtin_amdgcn_exp2f)
#define EXP2(x) __builtin_amdgcn_exp2f(x)
#else
#define EXP2(x) __expf(0.69314718056f * (x))
#endif

__device__ __forceinline__ unsigned pk2(float a, float b) {
  __hip_bfloat162 hh = __float22bfloat162_rn(make_float2(a, b));  // a -> low short
  unsigned u; __builtin_memcpy(&u, &hh, 4); return u;
}
__device__ __forceinline__ short f2bf(float f) {
  union { float f; unsigned u; } x; x.f = f;
  unsigned r = (x.u + 0x7fffu + ((x.u >> 16) & 1u)) >> 16;  // RNE
  return (short)r;
}
// x[32:63] <-> y[0:31]  (verified on HW by R4's passing run)
__device__ __forceinline__ void pl32swap(unsigned &x, unsigned &y) {
  asm("v_permlane32_swap_b32 %0, %1" : "+v"(x), "+v"(y));
}
// x[16:31]<->y[0:15], x[48:63]<->y[32:47]
__device__ __forceinline__ void pl16swap(unsigned &x, unsigned &y) {
  asm("v_permlane16_swap_b32 %0, %1" : "+v"(x), "+v"(y));
}

__global__ __launch_bounds__(512, 4) void attn_kernel(
    const float* __restrict__ Q, const float* __restrict__ K,
    const float* __restrict__ V, float* __restrict__ Out) {
  const int tid  = threadIdx.x;
  const int wave = tid >> 6, lane = tid & 63;
  const int quad = lane >> 4, l16 = lane & 15;

  const int bh   = blockIdx.x >> 4;   // 16 q-blocks per head (128 q rows each)
  const int qblk = blockIdx.x & 15;

  const float* Qh = Q + (size_t)bh * DD * NN;
  const float* Kh = K + (size_t)bh * DD * NN;
  const float* Vh = V + (size_t)bh * DD * NN;
  float*       Oh = Out + (size_t)bh * NN * DD;

  __shared__ __align__(16) char ldsK[2][64 * ROWB];   // KT: [key][d] bf16, xor-swizzled 16B groups
  __shared__ __align__(16) char ldsV[2][64 * ROWB];   // V:  [v][key] bf16, linear

  // ---- Q as B-fragments (16x16x32): B[k=quad*8+j][n=l16]; one 16-q tile/wave ----
  const float qscale = 0.031881407f;  // log2(e)/sqrt(2048)
  const int qb = qblk * 128 + wave * 16;
  short8 bQ[2];
#pragma unroll
  for (int hh = 0; hh < 2; ++hh)
#pragma unroll
    for (int j = 0; j < 8; ++j) {
      int d = hh * 32 + quad * 8 + j;
      bQ[hh][j] = f2bf(Qh[(size_t)d * NN + qb + l16] * qscale);
    }

  f32x4 accO[4];   // O[q][v]: row q = quad*4+r, col v = vt*16+l16
#pragma unroll
  for (int vt = 0; vt < 4; ++vt) accO[vt] = (f32x4){0.f, 0.f, 0.f, 0.f};
  float lp = 0.f;  // sum of exp for q = qb + l16 (partial: this quad's keys)

  // ---- staging split over 512 threads ----
  const int ka = tid & 31, kg = tid >> 5;        // K: d-pair (2ka,2ka+1), keys kg*4..+3
  const int vv = tid >> 3, vko = (tid & 7) * 8;  // V: row v=vv, 8 keys
  const float* kbase0 = Kh + (size_t)(2 * ka) * NN + kg * 4;
  const float* kbase1 = kbase0 + NN;
  const float* vbase  = Vh + (size_t)vv * NN + vko;

  float kA[4], kB[4], vA[8];
  auto load_kv = [&](int k0) {
    float4 a = *(const float4*)(kbase0 + k0);
    float4 b = *(const float4*)(kbase1 + k0);
    kA[0] = a.x; kA[1] = a.y; kA[2] = a.z; kA[3] = a.w;
    kB[0] = b.x; kB[1] = b.y; kB[2] = b.z; kB[3] = b.w;
    const float4* pv = (const float4*)(vbase + k0);
    float4 c0 = pv[0], c1 = pv[1];
    vA[0] = c0.x; vA[1] = c0.y; vA[2] = c0.z; vA[3] = c0.w;
    vA[4] = c1.x; vA[5] = c1.y; vA[6] = c1.z; vA[7] = c1.w;
  };
  auto store_kv = [&](char* bK, char* bV) {
#pragma unroll
    for (int j = 0; j < 4; ++j) {
      int k = kg * 4 + j;
      int grp = (ka >> 2) ^ ((k >> 1) & 7);
      *(unsigned*)&bK[k * ROWB + grp * 16 + (ka & 3) * 4] = pk2(kA[j], kB[j]);
    }
    uint4 w = make_uint4(pk2(vA[0], vA[1]), pk2(vA[2], vA[3]),
                         pk2(vA[4], vA[5]), pk2(vA[6], vA[7]));
    *(uint4*)&bV[vv * ROWB + vko * 2] = w;
  };

  // ---- prologue: stage chunk 0 ----
  load_kv(0);
  store_kv(ldsK[0], ldsV[0]);
  __syncthreads();

  const int swr = l16 >> 1;   // KT read-side xor swizzle

  for (int it = 0; it < 32; ++it) {
    const int cur = it & 1;
    // prefetch next chunk into registers (wrapped on last iter; result unused)
    load_kv(((it + 1) & 31) * 64);

    const char* cK = ldsK[cur];
    const char* cV = ldsV[cur];

    // ---- S^T per 16-key tile: A=KT frag, B=Q regs; exp2+pack immediately ----
    // D layout: lane holds S^T[key=kt*16+quad*4+r][q=l16], r=0..3
    unsigned u[4][2];   // u[kt][s] = keys kt*16 + quad*4 + 2s + {0,1}
#pragma unroll
    for (int kt = 0; kt < 4; ++kt) {
      const char* row = &cK[(kt * 16 + l16) * ROWB];
      short8 aK0 = *(const short8*)&row[(quad ^ swr) * 16];
      short8 aK1 = *(const short8*)&row[((4 + quad) ^ swr) * 16];
      f32x4 z = (f32x4){0.f, 0.f, 0.f, 0.f};
      f32x4 sT = __builtin_amdgcn_mfma_f32_16x16x32_bf16(aK0, bQ[0], z, 0, 0, 0);
      sT = __builtin_amdgcn_mfma_f32_16x16x32_bf16(aK1, bQ[1], sT, 0, 0, 0);
      float p0 = EXP2(sT[0]), p1 = EXP2(sT[1]);
      float p2 = EXP2(sT[2]), p3 = EXP2(sT[3]);
      lp += (p0 + p1) + (p2 + p3);
      u[kt][0] = pk2(p0, p1);
      u[kt][1] = pk2(p2, p3);
    }

    // ---- A-frag assembly: target (quad g, u32 c) <- quad (2g+(c>>1))&3,
    //      tile g>>1, slot c&1.  One pl32swap + one pl16swap yields (c, c+2). ----
#pragma unroll
    for (int ks = 0; ks < 2; ++ks) {   // 32-key step: tiles 2ks, 2ks+1
      unsigned c0 = u[2 * ks][0], c2 = u[2 * ks + 1][0];
      pl32swap(c0, c2); pl16swap(c0, c2);
      unsigned c1 = u[2 * ks][1], c3 = u[2 * ks + 1][1];
      pl32swap(c1, c3); pl16swap(c1, c3);
      short8 aP;
      { unsigned w[4] = {c0, c1, c2, c3}; __builtin_memcpy(&aP, w, 16); }
#pragma unroll
      for (int vt = 0; vt < 4; ++vt) {
        short8 bVf = *(const short8*)&cV[(vt * 16 + l16) * ROWB + ks * 64 + quad * 16];
        accO[vt] = __builtin_amdgcn_mfma_f32_16x16x32_bf16(aP, bVf, accO[vt], 0, 0, 0);
      }
    }

    // ---- write prefetched chunk into the other buffer, single barrier ----
    store_kv(ldsK[cur ^ 1], ldsV[cur ^ 1]);
    __syncthreads();
  }

  // ---- epilogue: reduce l across quads, normalize, store ----
  float lv = lp;
  lv += __shfl_xor(lv, 16, 64);
  lv += __shfl_xor(lv, 32, 64);   // every lane: l for q = qb + l16
#pragma unroll
  for (int r = 0; r < 4; ++r) {
    float lr  = __shfl(lv, quad * 4 + r, 64);  // l for q-row quad*4+r
    float inv = 1.0f / lr;
    int q = qb + quad * 4 + r;
#pragma unroll
    for (int vt = 0; vt < 4; ++vt)
      Oh[(size_t)q * DD + vt * 16 + l16] = accO[vt][r] * inv;
  }
}

extern "C" void kernel_launch(void* const* d_in, const int* in_sizes, int n_in,
                              void* d_out, int out_size, void* d_ws, size_t ws_size,
                              hipStream_t stream) {
  const float* Q = (const float*)d_in[0];
  const float* K = (const float*)d_in[1];
  const float* V = (const float*)d_in[2];
  float* O = (float*)d_out;
  dim3 grid(2 * 16 * (NN / 128));  // 512 blocks, 8 waves, 128 q-rows each
  attn_kernel<<<grid, dim3(512), 0, stream>>>(Q, K, V, O);
}